// Round 9
// baseline (311.563 us; speedup 1.0000x reference)
//
#include <hip/hip_runtime.h>

// VQ-VAE quantizer: x [B=32, C=64, T=4096] f32, emb [K=1024, D=64] f32.
// Outputs flat f32: quant_out [B*C*T], codebook_loss [1], commitment_loss [1],
// idx [B*T] (as float).
//
// CORRECTNESS MODEL (validated R2..R9): checker recomputes the reference with
// numpy f32. d_np(k) = RN( fl(S+e2[k]) - 2*g_k ), g_k = sequential-k single-acc
// FMA chain (BLAS). d~64 -> grid ulp(64)=7.6e-6; near-ties decided by numpy's
// exact rounding. Screen: split-bf16 MFMA (x=xh+xl, e=eh+el; xh*eh + xh*el +
// xl*eh, f32 acc) -> |dot~ - g_k| <= ~1.5e-6. Scan u_k = fl(fl(S+e2[k])-2dot~)
// with np-exact fl(S+e2[k]). Certify winner iff v2-v1 > BAND (4e-5); else
// np-exact full rescan (packed-u64 (flip(d)<<10|k) min = value order +
// first-index tie-break). S,e2: numpy pairwise_sum of fl(v*v), n=64
// (8 accs stride-8, ((r0+r1)+(r2+r3))+((r4+r5)+(r6+r7))).
// DO NOT change fallback chain arithmetic/order or S/e2 pairwise pattern.
//
// Perf: R15 = champion, 192 total (main 124.5): flat K-loop + depth-1 SW
// pipeline. Failures: R11 (K-loop barriers), R12 (VGPR cap spill), R13
// (per-element frag assembly -> scratch), R14/R16 (scalar fallback = L2
// request-rate poison; also: non-main ~65us is FIXED harness overhead --
// R16 removed a kernel and it didn't move), R17/R18 (depth-2 deleted by the
// PRE-RA SCHEDULER sinking prefetch loads to uses; VGPR stuck at 64 under
// both launch_bounds(256,4) and waves_per_eu(4,4) -- budget was never the
// limiter, scheduling was).
// R19: R15 verbatim + depth-2 K-loop + ONE __builtin_amdgcn_sched_barrier(0)
// per iteration between prefetch-issue and kstep. Scheduling regions can't
// cross a barrier node -> loads can't sink -> live ranges span an iteration
// -> the pipeline physically exists. Auto-waitcnt becomes a counted wait.
// Checkpoint: VGPR ~90-110 = pinned (still 64 = go inline-asm next).

typedef unsigned long long u64;
typedef unsigned short u16;
typedef __attribute__((ext_vector_type(8))) short bf8_t;   // 8 bf16 (A/B frag)
typedef __attribute__((ext_vector_type(4))) float f4_t;    // 4 f32  (C/D frag)

#define KCB 1024
#define DD 64
#define BB 32
#define TT 4096
#define BT (BB * TT)
#define NELEM (BB * DD * TT)

#define RPB 128                // rows per block
#define NT 16                  // emb tiles (64 cands each)
#define FB_MAX 48
#define BAND 4e-5f

#define WS_LOSS 0
#define WS_E2 64
#define WS_EH 2048             // float offset: eh frag table (64Ki u16 = 128KB)
#define WS_EL 34816            // el frag table

static __device__ __forceinline__ u16 bf16rte(float f) {
    unsigned u = __float_as_uint(f);
    return (u16)((u + 0x7FFFu + ((u >> 16) & 1u)) >> 16);
}
static __device__ __forceinline__ unsigned flipf(float f) {
    unsigned u = __float_as_uint(f);
    return (u & 0x80000000u) ? ~u : (u | 0x80000000u);
}
// frag-order index within a 64-cand tile: cand n, dim d -> u16 index
static __device__ __forceinline__ int fragidx(int n, int d) {
    return 1024 * (n >> 4) + 512 * (d >> 5) + 128 * ((d >> 3) & 3)
         + 8 * (n & 15) + (d & 7);
}

// Prep: parallel (256 blocks x 256 thr; block owns 4 cands). np-exact e2 via
// LDS pairwise; split-bf16 frag-order tables; coalesced loads. UNCHANGED.
__global__ void vq_prep(const float* __restrict__ emb, float* __restrict__ ws) {
#pragma clang fp contract(off)
    const int tid = threadIdx.x;
    const int kl = tid >> 6, d = tid & 63;
    const int k = blockIdx.x * 4 + kl;
    if (blockIdx.x == 0 && tid == 0) ws[WS_LOSS] = 0.0f;
    __shared__ float sq[4][64];
    __shared__ float rsh[4][8];
    float v = emb[(size_t)k * DD + d];
    u16 hb = bf16rte(v);
    float hv = __uint_as_float((unsigned)hb << 16);
    u16 lb = bf16rte(v - hv);                  // v-hv exact (Sterbenz)
    u16* ehg = (u16*)(ws + WS_EH) + 4096 * (k >> 6);
    u16* elg = (u16*)(ws + WS_EL) + 4096 * (k >> 6);
    const int ia = fragidx(k & 63, d);
    ehg[ia] = hb; elg[ia] = lb;
    sq[kl][d] = v * v;                         // fl(e*e) individually rounded
    __syncthreads();
    if (tid < 32) {
        const int g = tid >> 3, j = tid & 7;
        float r = sq[g][j];
#pragma unroll
        for (int i = 1; i < 8; ++i) r += sq[g][8 * i + j];   // i ascending
        rsh[g][j] = r;
    }
    __syncthreads();
    if (tid < 4) {
        const float* r = rsh[tid];
        ws[WS_E2 + blockIdx.x * 4 + tid] =
            ((r[0] + r[1]) + (r[2] + r[3])) + ((r[4] + r[5]) + (r[6] + r[7]));
    }
}

__launch_bounds__(256, 4)
__global__ void vq_main(const float* __restrict__ x, const float* __restrict__ emb,
                        float* __restrict__ out, float* __restrict__ ws) {
#pragma clang fp contract(off)
    const int tid = threadIdx.x;
    const int lane = tid & 63;
    const int w = __builtin_amdgcn_readfirstlane(tid >> 6);
    const int l15 = lane & 15, q = lane >> 4;

    const int row0 = blockIdx.x * RPB;          // 128 | 4096 -> b uniform
    const int b = row0 >> 12;
    const int t0 = row0 & (TT - 1);

    // Arena: xhT 16K + xlT 16K (x split-bf16 frag tables; dead after A-frag
    // loads). Fallback overlays efs (64x65 f32 = 16640B) + xfb (48x65 f32).
    __shared__ __align__(16) char arena[32768];
    u16* xhT = (u16*)arena;
    u16* xlT = (u16*)(arena + 16384);
    float* efs = (float*)arena;
    float* xfb = (float*)(arena + 16640);

    __shared__ float e2l[KCB];                  // np-exact e2, 4KB
    __shared__ float Srow[RPB];
    __shared__ int kwin[RPB];
    __shared__ int fbrows[FB_MAX];
    __shared__ int fbcnt;
    __shared__ float bsum;

    if (tid == 0) { fbcnt = 0; bsum = 0.0f; }
#pragma unroll
    for (int i = tid; i < KCB; i += 256) e2l[i] = ws[WS_E2 + i];

    // x stage: thread r<128 owns a row -- np-exact S + split-bf16 frag writes.
    if (tid < RPB) {
        const int r = tid;
        const float* xr = x + (size_t)b * DD * TT + t0 + r;
        const int gb = 1024 * (r >> 4);
        float rr[8];
#pragma unroll
        for (int i = 0; i < 64; i += 8) {
#pragma unroll
            for (int j = 0; j < 8; ++j) {
                float v = xr[(size_t)(i + j) * TT];
                if (i == 0) rr[j] = v * v; else rr[j] += v * v;
                u16 hb = bf16rte(v);
                float hv = __uint_as_float((unsigned)hb << 16);
                u16 lb = bf16rte(v - hv);
                const int ia = gb + fragidx(r & 15, i + j);
                xhT[ia] = hb; xlT[ia] = lb;
            }
        }
        Srow[r] = ((rr[0] + rr[1]) + (rr[2] + rr[3])) + ((rr[4] + rr[5]) + (rr[6] + rr[7]));
    }
    __syncthreads();

    // A-frags: wave w owns row-groups 2w, 2w+1 (32 rows); loaded once
    // as whole bf8_t (ds_read_b128 -- codegen invariant, R13 lesson).
    bf8_t ah[2][2], al[2][2];
#pragma unroll
    for (int g = 0; g < 2; ++g) {
        const int gg = 2 * w + g;
        ah[g][0] = *(const bf8_t*)&xhT[1024 * gg + 8 * lane];
        ah[g][1] = *(const bf8_t*)&xhT[1024 * gg + 512 + 8 * lane];
        al[g][0] = *(const bf8_t*)&xlT[1024 * gg + 8 * lane];
        al[g][1] = *(const bf8_t*)&xlT[1024 * gg + 512 + 8 * lane];
    }
    float Sv[8];
#pragma unroll
    for (int g = 0; g < 2; ++g)
#pragma unroll
        for (int rg = 0; rg < 4; ++rg)
            Sv[4 * g + rg] = Srow[32 * w + 16 * g + 4 * q + rg];

    // In-register scan state: thread owns 8 rows (4q+rg in each group), cols
    // congruent to l15 (mod 16). All indices compile-time after unroll.
    float v1[8], v2[8], kf[8];
#pragma unroll
    for (int s = 0; s < 8; ++s) { v1[s] = 3.4e38f; v2[s] = 3.4e38f; kf[s] = 0.0f; }

    const u16* ehg = (const u16*)(ws + WS_EH);
    const u16* elg = (const u16*)(ws + WS_EL);

    // One K-step: 12 MFMA + scan for 16 candidates. Arithmetic identical to
    // R10 (same op sequence; 16*it+l15 == kb+l15; ascending-k first-min).
    auto kstep = [&](float e2v, float kcol,
                     bf8_t bh0, bf8_t bl0, bf8_t bh1, bf8_t bl1) {
#pragma unroll
        for (int g = 0; g < 2; ++g) {
            f4_t acc = (f4_t){0.f, 0.f, 0.f, 0.f};
            acc = __builtin_amdgcn_mfma_f32_16x16x32_bf16(ah[g][0], bh0, acc, 0, 0, 0);
            acc = __builtin_amdgcn_mfma_f32_16x16x32_bf16(ah[g][0], bl0, acc, 0, 0, 0);
            acc = __builtin_amdgcn_mfma_f32_16x16x32_bf16(al[g][0], bh0, acc, 0, 0, 0);
            acc = __builtin_amdgcn_mfma_f32_16x16x32_bf16(ah[g][1], bh1, acc, 0, 0, 0);
            acc = __builtin_amdgcn_mfma_f32_16x16x32_bf16(ah[g][1], bl1, acc, 0, 0, 0);
            acc = __builtin_amdgcn_mfma_f32_16x16x32_bf16(al[g][1], bh1, acc, 0, 0, 0);
            // D: col=lane&15, row-in-16 = 4q+rg  [m89; R8/R9-validated]
#pragma unroll
            for (int rg = 0; rg < 4; ++rg) {
                const int s = 4 * g + rg;
                float ck = Sv[s] + e2v;                    // np-exact fl(S+e2)
                float u = __builtin_fmaf(-2.0f, acc[rg], ck);
                bool lt = u < v1[s];                       // strict: first-min
                float sp = lt ? v1[s] : u;
                v2[s] = fminf(v2[s], sp);
                kf[s] = lt ? kcol : kf[s];
                v1[s] = fminf(v1[s], u);
            }
        }
    };

    // Flat K-loop, depth-2 SW pipeline, schedule-pinned: prefetch for it+2
    // is issued, then sched_barrier(0) makes sinking those loads into/past
    // kstep illegal -> values stay live across iterations -> real pipeline.
    // NO thread barriers. Tables contiguous in it (1024*it).
    bf8_t cbh0 = *(const bf8_t*)&ehg[8 * lane];
    bf8_t cbh1 = *(const bf8_t*)&ehg[512 + 8 * lane];
    bf8_t cbl0 = *(const bf8_t*)&elg[8 * lane];
    bf8_t cbl1 = *(const bf8_t*)&elg[512 + 8 * lane];
    float ce2 = e2l[l15];
    bf8_t dbh0 = *(const bf8_t*)&ehg[1024 + 8 * lane];
    bf8_t dbh1 = *(const bf8_t*)&ehg[1024 + 512 + 8 * lane];
    bf8_t dbl0 = *(const bf8_t*)&elg[1024 + 8 * lane];
    bf8_t dbl1 = *(const bf8_t*)&elg[1024 + 512 + 8 * lane];
    float de2 = e2l[16 + l15];
#pragma unroll 2
    for (int it = 0; it < 62; ++it) {
        const u16* bhp = ehg + 1024 * (it + 2);
        const u16* blp = elg + 1024 * (it + 2);
        bf8_t nbh0 = *(const bf8_t*)&bhp[8 * lane];
        bf8_t nbh1 = *(const bf8_t*)&bhp[512 + 8 * lane];
        bf8_t nbl0 = *(const bf8_t*)&blp[8 * lane];
        bf8_t nbl1 = *(const bf8_t*)&blp[512 + 8 * lane];
        float ne2 = e2l[16 * (it + 2) + l15];
        __builtin_amdgcn_sched_barrier(0);     // pin: loads issue before kstep
        kstep(ce2, (float)(16 * it + l15), cbh0, cbl0, cbh1, cbl1);
        cbh0 = dbh0; cbh1 = dbh1; cbl0 = dbl0; cbl1 = dbl1; ce2 = de2;
        dbh0 = nbh0; dbh1 = nbh1; dbl0 = nbl0; dbl1 = nbl1; de2 = ne2;
    }
    kstep(ce2, (float)(16 * 62 + l15), cbh0, cbl0, cbh1, cbl1);
    kstep(de2, (float)(16 * 63 + l15), dbh0, dbl0, dbh1, dbl1);

    // Merge top-2 across the 16 lanes of each col-class (butterfly, width 16).
#pragma unroll
    for (int m = 1; m < 16; m <<= 1) {
#pragma unroll
        for (int s = 0; s < 8; ++s) {
            float ov1 = __shfl_xor(v1[s], m, 16);
            float okf = __shfl_xor(kf[s], m, 16);
            float ov2 = __shfl_xor(v2[s], m, 16);
            float nmx = fmaxf(v1[s], ov1);
            v2[s] = fminf(fminf(v2[s], ov2), nmx);
            bool lt = ov1 < v1[s];
            kf[s] = lt ? okf : kf[s];
            v1[s] = fminf(v1[s], ov1);
        }
    }
    if (l15 == 0) {
#pragma unroll
        for (int g = 0; g < 2; ++g)
#pragma unroll
            for (int rg = 0; rg < 4; ++rg) {
                const int s = 4 * g + rg;
                const int r = 32 * w + 16 * g + 4 * q + rg;
                kwin[r] = (int)kf[s];
                if (v2[s] <= v1[s] + BAND) {    // near-tie (incl. exact ties)
                    int i = atomicAdd(&fbcnt, 1);
                    if (i < FB_MAX) fbrows[i] = r;
                }
            }
    }
    __syncthreads();

    // FALLBACK: np-exact full rescan for near-tie rows (~1%). Uniform skip.
    // LDS-staged (coalesced emb reads, reused across slots) -- R15-verbatim;
    // scalar per-lane emb reads are L2 request-rate poison (R14/R16 lesson).
    const int cnt = min(fbcnt, FB_MAX);
    if (cnt > 0) {
        for (int i = tid; i < cnt * 64; i += 256) {
            int fi = i >> 6, l = i & 63;
            xfb[fi * 65 + l] = x[(size_t)b * DD * TT + (size_t)l * TT + t0 + fbrows[fi]];
        }
        u64 pmin[12];
#pragma unroll
        for (int sl = 0; sl < 12; ++sl) pmin[sl] = ~0ull;
#pragma unroll 1
        for (int T2 = 0; T2 < NT; ++T2) {
            __syncthreads();
            {   // stage f32 e tile, stride 65 (chain reads conflict-free)
                const int n = tid >> 2, qd = (tid & 3) * 16;
                const float* sp = emb + (size_t)(T2 * 64 + n) * DD + qd;
                float* dp = efs + n * 65 + qd;
#pragma unroll
                for (int j = 0; j < 16; ++j) dp[j] = sp[j];
            }
            __syncthreads();
#pragma unroll
            for (int sl = 0; sl < 12; ++sl) {
                const int fi = w + 4 * sl;
                if (fi < cnt) {
                    float acc = 0.0f;
#pragma unroll
                    for (int i = 0; i < 64; ++i)   // np-exact seq-k chain
                        acc = __builtin_fmaf(efs[lane * 65 + i], xfb[fi * 65 + i], acc);
                    float ck = Srow[fbrows[fi]] + e2l[T2 * 64 + lane];
                    float u = __builtin_fmaf(-2.0f, acc, ck);
                    u64 pk = ((u64)flipf(u) << 10) | (unsigned)(T2 * 64 + lane);
                    pmin[sl] = pmin[sl] < pk ? pmin[sl] : pk;
                }
            }
        }
#pragma unroll
        for (int sl = 0; sl < 12; ++sl) {
            const int fi = w + 4 * sl;
            if (fi < cnt) {
                u64 pk = pmin[sl];
#pragma unroll
                for (int dl = 32; dl > 0; dl >>= 1) {
                    u64 o = __shfl_xor(pk, dl);
                    pk = o < pk ? o : pk;
                }
                if (lane == 0) kwin[fbrows[fi]] = (int)(pk & 1023u);
            }
        }
        __syncthreads();
    }

    // Epilogue: idx, quant_out = emb[kwin] (exact), loss sum.
    if (tid < RPB) out[NELEM + 2 + row0 + tid] = (float)kwin[tid];

    const int r = tid & 127, c0 = (tid >> 7) * 32;
    const int kw = kwin[r];
    const float* eqr = emb + (size_t)kw * DD;
    float lsum = 0.0f;
#pragma unroll 8
    for (int i = 0; i < 32; ++i) {
        const int c = c0 + i;
        const size_t o = (size_t)b * DD * TT + (size_t)c * TT + t0 + r;
        float qv = eqr[c];
        float xv = x[o];
        out[o] = qv;
        float a = qv - xv;
        lsum = __builtin_fmaf(a, a, lsum);
    }
#pragma unroll
    for (int off = 32; off > 0; off >>= 1) lsum += __shfl_down(lsum, off);
    if (lane == 0) atomicAdd(&bsum, lsum);
    __syncthreads();
    if (tid == 0) atomicAdd(ws + WS_LOSS, bsum);
}

__global__ void vq_finalize(const float* __restrict__ ws, float* __restrict__ out) {
    if (threadIdx.x == 0 && blockIdx.x == 0) {
        float M = ws[WS_LOSS] / (float)NELEM;
        out[NELEM + 0] = M;           // codebook_loss
        out[NELEM + 1] = 0.25f * M;   // commitment_loss = BETA * same mean
    }
}

extern "C" void kernel_launch(void* const* d_in, const int* in_sizes, int n_in,
                              void* d_out, int out_size, void* d_ws, size_t ws_size,
                              hipStream_t stream) {
    const float* x = (const float*)d_in[0];
    const float* emb = (const float*)d_in[1];
    float* out = (float*)d_out;
    float* ws = (float*)d_ws;

    vq_prep<<<KCB / 4, 256, 0, stream>>>(emb, ws);
    vq_main<<<BT / RPB, 256, 0, stream>>>(x, emb, out, ws);
    vq_finalize<<<1, 64, 0, stream>>>(ws, out);
}

// Round 10
// 198.327 us; speedup vs baseline: 1.5710x; 1.5710x over previous
//
#include <hip/hip_runtime.h>

// VQ-VAE quantizer: x [B=32, C=64, T=4096] f32, emb [K=1024, D=64] f32.
// Outputs flat f32: quant_out [B*C*T], codebook_loss [1], commitment_loss [1],
// idx [B*T] (as float).
//
// CORRECTNESS MODEL (validated R2..R9): checker recomputes the reference with
// numpy f32. d_np(k) = RN( fl(S+e2[k]) - 2*g_k ), g_k = sequential-k single-acc
// FMA chain (BLAS). d~64 -> grid ulp(64)=7.6e-6; near-ties decided by numpy's
// exact rounding. Screen: split-bf16 MFMA (x=xh+xl, e=eh+el; xh*eh + xh*el +
// xl*eh, f32 acc) -> |dot~ - g_k| <= ~1.5e-6. Scan u_k = fl(fl(S+e2[k])-2dot~)
// with np-exact fl(S+e2[k]). Certify winner iff v2-v1 > BAND (4e-5); else
// np-exact full rescan (packed-u64 (flip(d)<<10|k) min = value order +
// first-index tie-break). S,e2: numpy pairwise_sum of fl(v*v), n=64
// (8 accs stride-8, ((r0+r1)+(r2+r3))+((r4+r5)+(r6+r7))).
// DO NOT change fallback chain arithmetic/order or S/e2 pairwise pattern.
//
// Perf: R15 = champion, 192 total (main 124.5). Failures: R11 (synchronous
// LDS staging w/ drains), R12 (VGPR cap spill), R13 (per-element frag
// assembly -> scratch), R14/R16 (scalar fallback = L2 request-rate poison),
// R17/R18 (depth-2 deleted by scheduler; VGPR pinned at 64 by allocator),
// R19 (sched_barrier pinned loads -> allocator SPILLED them: WRITE 222MB).
// Triangulated fact: extra pipeline depth cannot live in VGPRs (64 is full:
// A 32 + scan 24 + Sv/misc).
// R20: depth lives in LDS instead. K-loop B-tiles staged per-BLOCK via
// __builtin_amdgcn_global_load_lds (zero VGPR cost) into 3x4KB buffers in
// the dead x-frag arena; each wave DMAs one 1KB piece of tile it+2 per
// iteration; counted s_waitcnt vmcnt(1) + RAW s_barrier (no auto-drain,
// unlike __syncthreads -- loads stay in flight across barriers, T3/m218).
// 3 buffers -> DMA target was last read two barriers ago (no race).
// Also cuts L2 B-traffic 4x (waves share the block's stage: 1GB -> 256MB).
// B bytes copied verbatim -> kstep arithmetic bit-identical to R15.

typedef unsigned long long u64;
typedef unsigned short u16;
typedef __attribute__((ext_vector_type(8))) short bf8_t;   // 8 bf16 (A/B frag)
typedef __attribute__((ext_vector_type(4))) float f4_t;    // 4 f32  (C/D frag)

#define KCB 1024
#define DD 64
#define BB 32
#define TT 4096
#define BT (BB * TT)
#define NELEM (BB * DD * TT)

#define RPB 128                // rows per block
#define NT 16                  // emb tiles (64 cands each)
#define FB_MAX 48
#define BAND 4e-5f

#define WS_LOSS 0
#define WS_E2 64
#define WS_EH 2048             // float offset: eh frag table (64Ki u16 = 128KB)
#define WS_EL 34816            // el frag table

static __device__ __forceinline__ u16 bf16rte(float f) {
    unsigned u = __float_as_uint(f);
    return (u16)((u + 0x7FFFu + ((u >> 16) & 1u)) >> 16);
}
static __device__ __forceinline__ unsigned flipf(float f) {
    unsigned u = __float_as_uint(f);
    return (u & 0x80000000u) ? ~u : (u | 0x80000000u);
}
// frag-order index within a 64-cand tile: cand n, dim d -> u16 index
static __device__ __forceinline__ int fragidx(int n, int d) {
    return 1024 * (n >> 4) + 512 * (d >> 5) + 128 * ((d >> 3) & 3)
         + 8 * (n & 15) + (d & 7);
}
// async global->LDS, 16B/lane: LDS dest = wave-uniform base + lane*16,
// global src per-lane. Zero VGPR data cost; tracked by vmcnt.
static __device__ __forceinline__ void gload_lds16(const void* g, void* l) {
    __builtin_amdgcn_global_load_lds(
        (const __attribute__((address_space(1))) void*)g,
        (__attribute__((address_space(3))) void*)l, 16, 0, 0);
}

// Prep: parallel (256 blocks x 256 thr; block owns 4 cands). np-exact e2 via
// LDS pairwise; split-bf16 frag-order tables; coalesced loads. UNCHANGED.
__global__ void vq_prep(const float* __restrict__ emb, float* __restrict__ ws) {
#pragma clang fp contract(off)
    const int tid = threadIdx.x;
    const int kl = tid >> 6, d = tid & 63;
    const int k = blockIdx.x * 4 + kl;
    if (blockIdx.x == 0 && tid == 0) ws[WS_LOSS] = 0.0f;
    __shared__ float sq[4][64];
    __shared__ float rsh[4][8];
    float v = emb[(size_t)k * DD + d];
    u16 hb = bf16rte(v);
    float hv = __uint_as_float((unsigned)hb << 16);
    u16 lb = bf16rte(v - hv);                  // v-hv exact (Sterbenz)
    u16* ehg = (u16*)(ws + WS_EH) + 4096 * (k >> 6);
    u16* elg = (u16*)(ws + WS_EL) + 4096 * (k >> 6);
    const int ia = fragidx(k & 63, d);
    ehg[ia] = hb; elg[ia] = lb;
    sq[kl][d] = v * v;                         // fl(e*e) individually rounded
    __syncthreads();
    if (tid < 32) {
        const int g = tid >> 3, j = tid & 7;
        float r = sq[g][j];
#pragma unroll
        for (int i = 1; i < 8; ++i) r += sq[g][8 * i + j];   // i ascending
        rsh[g][j] = r;
    }
    __syncthreads();
    if (tid < 4) {
        const float* r = rsh[tid];
        ws[WS_E2 + blockIdx.x * 4 + tid] =
            ((r[0] + r[1]) + (r[2] + r[3])) + ((r[4] + r[5]) + (r[6] + r[7]));
    }
}

__launch_bounds__(256, 4)
__global__ void vq_main(const float* __restrict__ x, const float* __restrict__ emb,
                        float* __restrict__ out, float* __restrict__ ws) {
#pragma clang fp contract(off)
    const int tid = threadIdx.x;
    const int lane = tid & 63;
    const int w = __builtin_amdgcn_readfirstlane(tid >> 6);
    const int l15 = lane & 15, q = lane >> 4;

    const int row0 = blockIdx.x * RPB;          // 128 | 4096 -> b uniform
    const int b = row0 >> 12;
    const int t0 = row0 & (TT - 1);

    // Arena: [stage] xhT 16K + xlT 16K -> [K-loop] 3x4KB B DMA buffers at
    // +0/+4096/+8192 -> [fallback] efs (16640B) + xfb (48x65 f32).
    __shared__ __align__(16) char arena[32768];
    u16* xhT = (u16*)arena;
    u16* xlT = (u16*)(arena + 16384);
    float* efs = (float*)arena;
    float* xfb = (float*)(arena + 16640);

    __shared__ float e2l[KCB];                  // np-exact e2, 4KB
    __shared__ float Srow[RPB];
    __shared__ int kwin[RPB];
    __shared__ int fbrows[FB_MAX];
    __shared__ int fbcnt;
    __shared__ float bsum;

    if (tid == 0) { fbcnt = 0; bsum = 0.0f; }
#pragma unroll
    for (int i = tid; i < KCB; i += 256) e2l[i] = ws[WS_E2 + i];

    // x stage: thread r<128 owns a row -- np-exact S + split-bf16 frag writes.
    if (tid < RPB) {
        const int r = tid;
        const float* xr = x + (size_t)b * DD * TT + t0 + r;
        const int gb = 1024 * (r >> 4);
        float rr[8];
#pragma unroll
        for (int i = 0; i < 64; i += 8) {
#pragma unroll
            for (int j = 0; j < 8; ++j) {
                float v = xr[(size_t)(i + j) * TT];
                if (i == 0) rr[j] = v * v; else rr[j] += v * v;
                u16 hb = bf16rte(v);
                float hv = __uint_as_float((unsigned)hb << 16);
                u16 lb = bf16rte(v - hv);
                const int ia = gb + fragidx(r & 15, i + j);
                xhT[ia] = hb; xlT[ia] = lb;
            }
        }
        Srow[r] = ((rr[0] + rr[1]) + (rr[2] + rr[3])) + ((rr[4] + rr[5]) + (rr[6] + rr[7]));
    }
    __syncthreads();

    // A-frags: wave w owns row-groups 2w, 2w+1 (32 rows); loaded once
    // as whole bf8_t (ds_read_b128 -- codegen invariant, R13 lesson).
    bf8_t ah[2][2], al[2][2];
#pragma unroll
    for (int g = 0; g < 2; ++g) {
        const int gg = 2 * w + g;
        ah[g][0] = *(const bf8_t*)&xhT[1024 * gg + 8 * lane];
        ah[g][1] = *(const bf8_t*)&xhT[1024 * gg + 512 + 8 * lane];
        al[g][0] = *(const bf8_t*)&xlT[1024 * gg + 8 * lane];
        al[g][1] = *(const bf8_t*)&xlT[1024 * gg + 512 + 8 * lane];
    }
    float Sv[8];
#pragma unroll
    for (int g = 0; g < 2; ++g)
#pragma unroll
        for (int rg = 0; rg < 4; ++rg)
            Sv[4 * g + rg] = Srow[32 * w + 16 * g + 4 * q + rg];

    // In-register scan state: thread owns 8 rows (4q+rg in each group), cols
    // congruent to l15 (mod 16). All indices compile-time after unroll.
    float v1[8], v2[8], kf[8];
#pragma unroll
    for (int s = 0; s < 8; ++s) { v1[s] = 3.4e38f; v2[s] = 3.4e38f; kf[s] = 0.0f; }

    const u16* ehg = (const u16*)(ws + WS_EH);
    const u16* elg = (const u16*)(ws + WS_EL);

    // One K-step: 12 MFMA + scan for 16 candidates. Arithmetic identical to
    // R10/R15 (same op sequence; 16*it+l15 == kb+l15; ascending-k first-min).
    auto kstep = [&](float e2v, float kcol,
                     bf8_t bh0, bf8_t bl0, bf8_t bh1, bf8_t bl1) {
#pragma unroll
        for (int g = 0; g < 2; ++g) {
            f4_t acc = (f4_t){0.f, 0.f, 0.f, 0.f};
            acc = __builtin_amdgcn_mfma_f32_16x16x32_bf16(ah[g][0], bh0, acc, 0, 0, 0);
            acc = __builtin_amdgcn_mfma_f32_16x16x32_bf16(ah[g][0], bl0, acc, 0, 0, 0);
            acc = __builtin_amdgcn_mfma_f32_16x16x32_bf16(al[g][0], bh0, acc, 0, 0, 0);
            acc = __builtin_amdgcn_mfma_f32_16x16x32_bf16(ah[g][1], bh1, acc, 0, 0, 0);
            acc = __builtin_amdgcn_mfma_f32_16x16x32_bf16(ah[g][1], bl1, acc, 0, 0, 0);
            acc = __builtin_amdgcn_mfma_f32_16x16x32_bf16(al[g][1], bh1, acc, 0, 0, 0);
            // D: col=lane&15, row-in-16 = 4q+rg  [m89; R8/R9-validated]
#pragma unroll
            for (int rg = 0; rg < 4; ++rg) {
                const int s = 4 * g + rg;
                float ck = Sv[s] + e2v;                    // np-exact fl(S+e2)
                float u = __builtin_fmaf(-2.0f, acc[rg], ck);
                bool lt = u < v1[s];                       // strict: first-min
                float sp = lt ? v1[s] : u;
                v2[s] = fminf(v2[s], sp);
                kf[s] = lt ? kcol : kf[s];
                v1[s] = fminf(v1[s], u);
            }
        }
    };

    // DMA piece assignment: tile it = 4KB = ehg 2KB + elg 2KB; wave w DMAs
    // piece w (1KB): w<2 -> ehg half w&1; w>=2 -> elg half w&1. LDS layout in
    // buffer (u16 idx): [0,512)=bh0 [512,1024)=bh1 [1024,1536)=bl0
    // [1536,2048)=bl1 -- matches read offsets below.
    const u16* psrc = (w < 2) ? ehg : elg;
    const int poff = (w & 1) * 512;            // u16 offset within src tile
    char* const pdst0 = arena + 1024 * w;      // byte offset of piece in buf
    auto issue = [&](int it2, int bufi) {
        gload_lds16(psrc + 1024 * it2 + poff + 8 * lane, pdst0 + 4096 * bufi);
    };

    // K-loop, LDS-DMA pipelined depth-2, 3 rotating buffers.
    // Per iteration: ds_read cur tile -> lgkmcnt(0) (regs valid; also: this
    // buffer's reads retired two barriers before anyone DMAs over it) ->
    // issue tile it+2 -> kstep -> vmcnt(1) (my piece of tile it+1 landed) ->
    // raw s_barrier (all pieces of it+1 visible; NO auto-drain so the it+2
    // loads stay in flight across it -- T3/m218 counted-vmcnt pattern).
    // A-frag reads above are protected from the first DMAs by __syncthreads.
    __syncthreads();
    issue(0, 0);
    issue(1, 1);
    asm volatile("s_waitcnt vmcnt(1)" ::: "memory");   // tile0 piece landed
    __builtin_amdgcn_s_barrier();                      // tile0 visible to all
#pragma unroll 3
    for (int it = 0; it < 60; ++it) {
        const int cur = it % 3;
        const u16* bb = (const u16*)(arena + 4096 * cur);
        bf8_t bh0 = *(const bf8_t*)&bb[8 * lane];
        bf8_t bh1 = *(const bf8_t*)&bb[512 + 8 * lane];
        bf8_t bl0 = *(const bf8_t*)&bb[1024 + 8 * lane];
        bf8_t bl1 = *(const bf8_t*)&bb[1536 + 8 * lane];
        const float e2v = e2l[16 * it + l15];
        asm volatile("s_waitcnt lgkmcnt(0)" ::: "memory");
        __builtin_amdgcn_sched_barrier(0);             // rule 18: pin order
        issue(it + 2, (it + 2) % 3);
        kstep(e2v, (float)(16 * it + l15), bh0, bl0, bh1, bl1);
        asm volatile("s_waitcnt vmcnt(1)" ::: "memory");
        __builtin_amdgcn_s_barrier();
    }
    // Tail: it = 60,61 (still issuing 62,63), then 62,63 (drain).
#pragma unroll 1
    for (int it = 60; it < 64; ++it) {
        const int cur = it % 3;
        const u16* bb = (const u16*)(arena + 4096 * cur);
        bf8_t bh0 = *(const bf8_t*)&bb[8 * lane];
        bf8_t bh1 = *(const bf8_t*)&bb[512 + 8 * lane];
        bf8_t bl0 = *(const bf8_t*)&bb[1024 + 8 * lane];
        bf8_t bl1 = *(const bf8_t*)&bb[1536 + 8 * lane];
        const float e2v = e2l[16 * it + l15];
        asm volatile("s_waitcnt lgkmcnt(0)" ::: "memory");
        __builtin_amdgcn_sched_barrier(0);
        if (it < 62) issue(it + 2, (it + 2) % 3);      // uniform branch
        kstep(e2v, (float)(16 * it + l15), bh0, bl0, bh1, bl1);
        if (it < 62) {
            asm volatile("s_waitcnt vmcnt(1)" ::: "memory");
        } else {
            asm volatile("s_waitcnt vmcnt(0)" ::: "memory");
        }
        __builtin_amdgcn_s_barrier();
    }

    // Merge top-2 across the 16 lanes of each col-class (butterfly, width 16).
#pragma unroll
    for (int m = 1; m < 16; m <<= 1) {
#pragma unroll
        for (int s = 0; s < 8; ++s) {
            float ov1 = __shfl_xor(v1[s], m, 16);
            float okf = __shfl_xor(kf[s], m, 16);
            float ov2 = __shfl_xor(v2[s], m, 16);
            float nmx = fmaxf(v1[s], ov1);
            v2[s] = fminf(fminf(v2[s], ov2), nmx);
            bool lt = ov1 < v1[s];
            kf[s] = lt ? okf : kf[s];
            v1[s] = fminf(v1[s], ov1);
        }
    }
    if (l15 == 0) {
#pragma unroll
        for (int g = 0; g < 2; ++g)
#pragma unroll
            for (int rg = 0; rg < 4; ++rg) {
                const int s = 4 * g + rg;
                const int r = 32 * w + 16 * g + 4 * q + rg;
                kwin[r] = (int)kf[s];
                if (v2[s] <= v1[s] + BAND) {    // near-tie (incl. exact ties)
                    int i = atomicAdd(&fbcnt, 1);
                    if (i < FB_MAX) fbrows[i] = r;
                }
            }
    }
    __syncthreads();

    // FALLBACK: np-exact full rescan for near-tie rows (~1%). Uniform skip.
    // LDS-staged (coalesced emb reads, reused across slots) -- R15-verbatim;
    // scalar per-lane emb reads are L2 request-rate poison (R14/R16 lesson).
    const int cnt = min(fbcnt, FB_MAX);
    if (cnt > 0) {
        for (int i = tid; i < cnt * 64; i += 256) {
            int fi = i >> 6, l = i & 63;
            xfb[fi * 65 + l] = x[(size_t)b * DD * TT + (size_t)l * TT + t0 + fbrows[fi]];
        }
        u64 pmin[12];
#pragma unroll
        for (int sl = 0; sl < 12; ++sl) pmin[sl] = ~0ull;
#pragma unroll 1
        for (int T2 = 0; T2 < NT; ++T2) {
            __syncthreads();
            {   // stage f32 e tile, stride 65 (chain reads conflict-free)
                const int n = tid >> 2, qd = (tid & 3) * 16;
                const float* sp = emb + (size_t)(T2 * 64 + n) * DD + qd;
                float* dp = efs + n * 65 + qd;
#pragma unroll
                for (int j = 0; j < 16; ++j) dp[j] = sp[j];
            }
            __syncthreads();
#pragma unroll
            for (int sl = 0; sl < 12; ++sl) {
                const int fi = w + 4 * sl;
                if (fi < cnt) {
                    float acc = 0.0f;
#pragma unroll
                    for (int i = 0; i < 64; ++i)   // np-exact seq-k chain
                        acc = __builtin_fmaf(efs[lane * 65 + i], xfb[fi * 65 + i], acc);
                    float ck = Srow[fbrows[fi]] + e2l[T2 * 64 + lane];
                    float u = __builtin_fmaf(-2.0f, acc, ck);
                    u64 pk = ((u64)flipf(u) << 10) | (unsigned)(T2 * 64 + lane);
                    pmin[sl] = pmin[sl] < pk ? pmin[sl] : pk;
                }
            }
        }
#pragma unroll
        for (int sl = 0; sl < 12; ++sl) {
            const int fi = w + 4 * sl;
            if (fi < cnt) {
                u64 pk = pmin[sl];
#pragma unroll
                for (int dl = 32; dl > 0; dl >>= 1) {
                    u64 o = __shfl_xor(pk, dl);
                    pk = o < pk ? o : pk;
                }
                if (lane == 0) kwin[fbrows[fi]] = (int)(pk & 1023u);
            }
        }
        __syncthreads();
    }

    // Epilogue: idx, quant_out = emb[kwin] (exact), loss sum.
    if (tid < RPB) out[NELEM + 2 + row0 + tid] = (float)kwin[tid];

    const int r = tid & 127, c0 = (tid >> 7) * 32;
    const int kw = kwin[r];
    const float* eqr = emb + (size_t)kw * DD;
    float lsum = 0.0f;
#pragma unroll 8
    for (int i = 0; i < 32; ++i) {
        const int c = c0 + i;
        const size_t o = (size_t)b * DD * TT + (size_t)c * TT + t0 + r;
        float qv = eqr[c];
        float xv = x[o];
        out[o] = qv;
        float a = qv - xv;
        lsum = __builtin_fmaf(a, a, lsum);
    }
#pragma unroll
    for (int off = 32; off > 0; off >>= 1) lsum += __shfl_down(lsum, off);
    if (lane == 0) atomicAdd(&bsum, lsum);
    __syncthreads();
    if (tid == 0) atomicAdd(ws + WS_LOSS, bsum);
}

__global__ void vq_finalize(const float* __restrict__ ws, float* __restrict__ out) {
    if (threadIdx.x == 0 && blockIdx.x == 0) {
        float M = ws[WS_LOSS] / (float)NELEM;
        out[NELEM + 0] = M;           // codebook_loss
        out[NELEM + 1] = 0.25f * M;   // commitment_loss = BETA * same mean
    }
}

extern "C" void kernel_launch(void* const* d_in, const int* in_sizes, int n_in,
                              void* d_out, int out_size, void* d_ws, size_t ws_size,
                              hipStream_t stream) {
    const float* x = (const float*)d_in[0];
    const float* emb = (const float*)d_in[1];
    float* out = (float*)d_out;
    float* ws = (float*)d_ws;

    vq_prep<<<KCB / 4, 256, 0, stream>>>(emb, ws);
    vq_main<<<BT / RPB, 256, 0, stream>>>(x, emb, out, ws);
    vq_finalize<<<1, 64, 0, stream>>>(ws, out);
}

// Round 11
// 188.720 us; speedup vs baseline: 1.6509x; 1.0509x over previous
//
#include <hip/hip_runtime.h>

// VQ-VAE quantizer: x [B=32, C=64, T=4096] f32, emb [K=1024, D=64] f32.
// Outputs flat f32: quant_out [B*C*T], codebook_loss [1], commitment_loss [1],
// idx [B*T] (as float).
//
// CORRECTNESS MODEL (validated R2..R9): checker recomputes the reference with
// numpy f32. d_np(k) = RN( fl(S+e2[k]) - 2*g_k ), g_k = sequential-k single-acc
// FMA chain (BLAS). d~64 -> grid ulp(64)=7.6e-6; near-ties decided by numpy's
// exact rounding. Screen: split-bf16 MFMA (x=xh+xl, e=eh+el; xh*eh + xh*el +
// xl*eh, f32 acc) -> |dot~ - g_k| <= ~1.5e-6. Scan u_k = fl(fl(S+e2[k])-2dot~)
// with np-exact fl(S+e2[k]). Certify winner iff v2-v1 > BAND (4e-5); else
// np-exact full rescan (packed-u64 (flip(d)<<10|k) min = value order +
// first-index tie-break). S,e2: numpy pairwise_sum of fl(v*v), n=64
// (8 accs stride-8, ((r0+r1)+(r2+r3))+((r4+r5)+(r6+r7))).
// DO NOT change fallback chain arithmetic/order or S/e2 pairwise pattern.
//
// Perf: R15 = champion, 192 total (main 124.5). R16-R20: five K-loop stall
// attacks (reg depth x3, LDS-DMA depth, barrier cadences) all 124-132us ->
// at 4 waves/SIMD the dependency structure is saturated. R12 autopsy:
// __launch_bounds__ 2nd arg acts as min BLOCKS/CU (CUDA semantics):
// (512,8) -> 16 waves/SIMD -> forced 32 VGPR -> spill. (256,4) -> 4/SIMD ->
// budget 128, allocator snaps to 64.
// R21: K-SPLIT WAVE DOUBLING. 512 threads, RPB=128, grid 1024: wave w owns
// row-groups of w&3 (per-wave code/regs IDENTICAL to R15, ~64 VGPR) and
// K-half h=w>>2 (it in [32h,32h+32)). LDS 38.4K -> 4 blocks/CU x 8 waves =
// 32 waves/CU (2x champion), B traffic unchanged (each wave reads its half).
// Cross-half merge = validated butterfly step (halves k-disjoint, ordered;
// strict-lt from half-1 keeps first-index ties); h=1 publishes 1.5KB LDS,
// h=0 merges + unchanged kwin/fb. Barriers added: 2, both outside K-loop.
// launch_bounds(512,4): budget >=64 under either semantics.

typedef unsigned long long u64;
typedef unsigned short u16;
typedef __attribute__((ext_vector_type(8))) short bf8_t;   // 8 bf16 (A/B frag)
typedef __attribute__((ext_vector_type(4))) float f4_t;    // 4 f32  (C/D frag)

#define KCB 1024
#define DD 64
#define BB 32
#define TT 4096
#define BT (BB * TT)
#define NELEM (BB * DD * TT)

#define RPB 128                // rows per block
#define NTHR 512               // 8 waves: 4 row-pair owners x 2 K-halves
#define NT 16                  // emb tiles (64 cands each)
#define FB_MAX 48
#define NSL 6                  // FB slots per wave: 8 waves * 6 = 48
#define BAND 4e-5f

#define WS_LOSS 0
#define WS_E2 64
#define WS_EH 2048             // float offset: eh frag table (64Ki u16 = 128KB)
#define WS_EL 34816            // el frag table

static __device__ __forceinline__ u16 bf16rte(float f) {
    unsigned u = __float_as_uint(f);
    return (u16)((u + 0x7FFFu + ((u >> 16) & 1u)) >> 16);
}
static __device__ __forceinline__ unsigned flipf(float f) {
    unsigned u = __float_as_uint(f);
    return (u & 0x80000000u) ? ~u : (u | 0x80000000u);
}
// frag-order index within a 64-cand tile: cand n, dim d -> u16 index
static __device__ __forceinline__ int fragidx(int n, int d) {
    return 1024 * (n >> 4) + 512 * (d >> 5) + 128 * ((d >> 3) & 3)
         + 8 * (n & 15) + (d & 7);
}

// Prep: parallel (256 blocks x 256 thr; block owns 4 cands). np-exact e2 via
// LDS pairwise; split-bf16 frag-order tables; coalesced loads. UNCHANGED.
__global__ void vq_prep(const float* __restrict__ emb, float* __restrict__ ws) {
#pragma clang fp contract(off)
    const int tid = threadIdx.x;
    const int kl = tid >> 6, d = tid & 63;
    const int k = blockIdx.x * 4 + kl;
    if (blockIdx.x == 0 && tid == 0) ws[WS_LOSS] = 0.0f;
    __shared__ float sq[4][64];
    __shared__ float rsh[4][8];
    float v = emb[(size_t)k * DD + d];
    u16 hb = bf16rte(v);
    float hv = __uint_as_float((unsigned)hb << 16);
    u16 lb = bf16rte(v - hv);                  // v-hv exact (Sterbenz)
    u16* ehg = (u16*)(ws + WS_EH) + 4096 * (k >> 6);
    u16* elg = (u16*)(ws + WS_EL) + 4096 * (k >> 6);
    const int ia = fragidx(k & 63, d);
    ehg[ia] = hb; elg[ia] = lb;
    sq[kl][d] = v * v;                         // fl(e*e) individually rounded
    __syncthreads();
    if (tid < 32) {
        const int g = tid >> 3, j = tid & 7;
        float r = sq[g][j];
#pragma unroll
        for (int i = 1; i < 8; ++i) r += sq[g][8 * i + j];   // i ascending
        rsh[g][j] = r;
    }
    __syncthreads();
    if (tid < 4) {
        const float* r = rsh[tid];
        ws[WS_E2 + blockIdx.x * 4 + tid] =
            ((r[0] + r[1]) + (r[2] + r[3])) + ((r[4] + r[5]) + (r[6] + r[7]));
    }
}

__launch_bounds__(NTHR, 4)
__global__ void vq_main(const float* __restrict__ x, const float* __restrict__ emb,
                        float* __restrict__ out, float* __restrict__ ws) {
#pragma clang fp contract(off)
    const int tid = threadIdx.x;
    const int lane = tid & 63;
    const int w = __builtin_amdgcn_readfirstlane(tid >> 6);   // 0..7
    const int w4 = w & 3;                       // row-pair owner
    const int h = w >> 2;                       // K-half: 0 -> it 0..31, 1 -> 32..63
    const int l15 = lane & 15, q = lane >> 4;

    const int row0 = blockIdx.x * RPB;          // 128 | 4096 -> b uniform
    const int b = row0 >> 12;
    const int t0 = row0 & (TT - 1);

    // Arena: [stage] xhT 16K + xlT 16K -> [merge] mv1/mv2/mkf (1.5KB) ->
    // [fallback] efs (16640B) + xfb (48x65 f32). Lifetimes barrier-separated.
    __shared__ __align__(16) char arena[32768];
    u16* xhT = (u16*)arena;
    u16* xlT = (u16*)(arena + 16384);
    float* mv1 = (float*)arena;                 // [128] half-1 v1
    float* mv2 = (float*)(arena + 512);         // [128] half-1 v2
    float* mkf = (float*)(arena + 1024);        // [128] half-1 kf
    float* efs = (float*)arena;
    float* xfb = (float*)(arena + 16640);

    __shared__ float e2l[KCB];                  // np-exact e2, 4KB
    __shared__ float Srow[RPB];
    __shared__ int kwin[RPB];
    __shared__ int fbrows[FB_MAX];
    __shared__ int fbcnt;
    __shared__ float bsum;

    if (tid == 0) { fbcnt = 0; bsum = 0.0f; }
#pragma unroll
    for (int i = tid; i < KCB; i += NTHR) e2l[i] = ws[WS_E2 + i];

    // x stage: thread r<128 owns a row -- np-exact S + split-bf16 frag writes.
    // (champion-verbatim; waves 2-7 wait at the barrier)
    if (tid < RPB) {
        const int r = tid;
        const float* xr = x + (size_t)b * DD * TT + t0 + r;
        const int gb = 1024 * (r >> 4);
        float rr[8];
#pragma unroll
        for (int i = 0; i < 64; i += 8) {
#pragma unroll
            for (int j = 0; j < 8; ++j) {
                float v = xr[(size_t)(i + j) * TT];
                if (i == 0) rr[j] = v * v; else rr[j] += v * v;
                u16 hb = bf16rte(v);
                float hv = __uint_as_float((unsigned)hb << 16);
                u16 lb = bf16rte(v - hv);
                const int ia = gb + fragidx(r & 15, i + j);
                xhT[ia] = hb; xlT[ia] = lb;
            }
        }
        Srow[r] = ((rr[0] + rr[1]) + (rr[2] + rr[3])) + ((rr[4] + rr[5]) + (rr[6] + rr[7]));
    }
    __syncthreads();

    // A-frags: wave w owns row-groups 2*w4, 2*w4+1 (32 rows); loaded once
    // as whole bf8_t (ds_read_b128 -- codegen invariant, R13 lesson).
    bf8_t ah[2][2], al[2][2];
#pragma unroll
    for (int g = 0; g < 2; ++g) {
        const int gg = 2 * w4 + g;
        ah[g][0] = *(const bf8_t*)&xhT[1024 * gg + 8 * lane];
        ah[g][1] = *(const bf8_t*)&xhT[1024 * gg + 512 + 8 * lane];
        al[g][0] = *(const bf8_t*)&xlT[1024 * gg + 8 * lane];
        al[g][1] = *(const bf8_t*)&xlT[1024 * gg + 512 + 8 * lane];
    }
    float Sv[8];
#pragma unroll
    for (int g = 0; g < 2; ++g)
#pragma unroll
        for (int rg = 0; rg < 4; ++rg)
            Sv[4 * g + rg] = Srow[32 * w4 + 16 * g + 4 * q + rg];
    __syncthreads();                           // arena officially dead for all

    // In-register scan state: thread owns 8 rows (4q+rg in each group), cols
    // congruent to l15 (mod 16). All indices compile-time after unroll.
    float v1[8], v2[8], kf[8];
#pragma unroll
    for (int s = 0; s < 8; ++s) { v1[s] = 3.4e38f; v2[s] = 3.4e38f; kf[s] = 0.0f; }

    const u16* ehg = (const u16*)(ws + WS_EH);
    const u16* elg = (const u16*)(ws + WS_EL);

    // One K-step: 12 MFMA + scan for 16 candidates. Arithmetic identical to
    // R10/R15 (same op sequence; 16*it+l15 == kb+l15; ascending-k first-min).
    auto kstep = [&](float e2v, float kcol,
                     bf8_t bh0, bf8_t bl0, bf8_t bh1, bf8_t bl1) {
#pragma unroll
        for (int g = 0; g < 2; ++g) {
            f4_t acc = (f4_t){0.f, 0.f, 0.f, 0.f};
            acc = __builtin_amdgcn_mfma_f32_16x16x32_bf16(ah[g][0], bh0, acc, 0, 0, 0);
            acc = __builtin_amdgcn_mfma_f32_16x16x32_bf16(ah[g][0], bl0, acc, 0, 0, 0);
            acc = __builtin_amdgcn_mfma_f32_16x16x32_bf16(al[g][0], bh0, acc, 0, 0, 0);
            acc = __builtin_amdgcn_mfma_f32_16x16x32_bf16(ah[g][1], bh1, acc, 0, 0, 0);
            acc = __builtin_amdgcn_mfma_f32_16x16x32_bf16(ah[g][1], bl1, acc, 0, 0, 0);
            acc = __builtin_amdgcn_mfma_f32_16x16x32_bf16(al[g][1], bh1, acc, 0, 0, 0);
            // D: col=lane&15, row-in-16 = 4q+rg  [m89; R8/R9-validated]
#pragma unroll
            for (int rg = 0; rg < 4; ++rg) {
                const int s = 4 * g + rg;
                float ck = Sv[s] + e2v;                    // np-exact fl(S+e2)
                float u = __builtin_fmaf(-2.0f, acc[rg], ck);
                bool lt = u < v1[s];                       // strict: first-min
                float sp = lt ? v1[s] : u;
                v2[s] = fminf(v2[s], sp);
                kf[s] = lt ? kcol : kf[s];
                v1[s] = fminf(v1[s], u);
            }
        }
    };

    // Flat K-half loop, software-pipelined depth-1 (R15-verbatim structure):
    // wave scans it in [32h, 32h+32). NO barriers. Last prefetch <= 63.
    const int it0 = 32 * h;
    bf8_t cbh0 = *(const bf8_t*)&ehg[1024 * it0 + 8 * lane];
    bf8_t cbh1 = *(const bf8_t*)&ehg[1024 * it0 + 512 + 8 * lane];
    bf8_t cbl0 = *(const bf8_t*)&elg[1024 * it0 + 8 * lane];
    bf8_t cbl1 = *(const bf8_t*)&elg[1024 * it0 + 512 + 8 * lane];
    float ce2 = e2l[16 * it0 + l15];
#pragma unroll 2
    for (int io = 0; io < 31; ++io) {
        const int it = it0 + io;
        const u16* bhp = ehg + 1024 * (it + 1);
        const u16* blp = elg + 1024 * (it + 1);
        bf8_t nbh0 = *(const bf8_t*)&bhp[8 * lane];
        bf8_t nbh1 = *(const bf8_t*)&bhp[512 + 8 * lane];
        bf8_t nbl0 = *(const bf8_t*)&blp[8 * lane];
        bf8_t nbl1 = *(const bf8_t*)&blp[512 + 8 * lane];
        float ne2 = e2l[16 * (it + 1) + l15];
        kstep(ce2, (float)(16 * it + l15), cbh0, cbl0, cbh1, cbl1);
        cbh0 = nbh0; cbh1 = nbh1; cbl0 = nbl0; cbl1 = nbl1; ce2 = ne2;
    }
    kstep(ce2, (float)(16 * (it0 + 31) + l15), cbh0, cbl0, cbh1, cbl1);

    // Merge top-2 across the 16 lanes of each col-class (butterfly, width 16).
#pragma unroll
    for (int m = 1; m < 16; m <<= 1) {
#pragma unroll
        for (int s = 0; s < 8; ++s) {
            float ov1 = __shfl_xor(v1[s], m, 16);
            float okf = __shfl_xor(kf[s], m, 16);
            float ov2 = __shfl_xor(v2[s], m, 16);
            float nmx = fmaxf(v1[s], ov1);
            v2[s] = fminf(fminf(v2[s], ov2), nmx);
            bool lt = ov1 < v1[s];
            kf[s] = lt ? okf : kf[s];
            v1[s] = fminf(v1[s], ov1);
        }
    }

    // Cross-half merge: half-1 publishes; half-0 merges (keeps self on tie --
    // all half-0 k < all half-1 k within a col-class, so first-index holds).
    if (h == 1 && l15 == 0) {
#pragma unroll
        for (int g = 0; g < 2; ++g)
#pragma unroll
            for (int rg = 0; rg < 4; ++rg) {
                const int s = 4 * g + rg;
                const int r = 32 * w4 + 16 * g + 4 * q + rg;
                mv1[r] = v1[s]; mv2[r] = v2[s]; mkf[r] = kf[s];
            }
    }
    __syncthreads();
    if (h == 0 && l15 == 0) {
#pragma unroll
        for (int g = 0; g < 2; ++g)
#pragma unroll
            for (int rg = 0; rg < 4; ++rg) {
                const int s = 4 * g + rg;
                const int r = 32 * w4 + 16 * g + 4 * q + rg;
                float v1b = mv1[r], v2b = mv2[r], kfb = mkf[r];
                float nmx = fmaxf(v1[s], v1b);
                float v2m = fminf(fminf(v2[s], v2b), nmx);
                bool ltb = v1b < v1[s];                    // strict: half-0 on tie
                float kfm = ltb ? kfb : kf[s];
                float v1m = fminf(v1[s], v1b);
                kwin[r] = (int)kfm;
                if (v2m <= v1m + BAND) {    // near-tie (incl. exact ties)
                    int i = atomicAdd(&fbcnt, 1);
                    if (i < FB_MAX) fbrows[i] = r;
                }
            }
    }
    __syncthreads();

    // FALLBACK: np-exact full rescan for near-tie rows (~1%). Uniform skip.
    // LDS-staged (coalesced emb reads, reused across slots) -- R15-verbatim;
    // scalar per-lane emb reads are L2 request-rate poison (R14/R16 lesson).
    const int cnt = min(fbcnt, FB_MAX);
    if (cnt > 0) {
        for (int i = tid; i < cnt * 64; i += NTHR) {
            int fi = i >> 6, l = i & 63;
            xfb[fi * 65 + l] = x[(size_t)b * DD * TT + (size_t)l * TT + t0 + fbrows[fi]];
        }
        u64 pmin[NSL];
#pragma unroll
        for (int sl = 0; sl < NSL; ++sl) pmin[sl] = ~0ull;
#pragma unroll 1
        for (int T2 = 0; T2 < NT; ++T2) {
            __syncthreads();
            {   // stage f32 e tile, stride 65 (chain reads conflict-free)
                const int n = tid >> 3, qd = (tid & 7) * 8;
                const float* sp = emb + (size_t)(T2 * 64 + n) * DD + qd;
                float* dp = efs + n * 65 + qd;
#pragma unroll
                for (int j = 0; j < 8; ++j) dp[j] = sp[j];
            }
            __syncthreads();
#pragma unroll
            for (int sl = 0; sl < NSL; ++sl) {
                const int fi = w + 8 * sl;
                if (fi < cnt) {
                    float acc = 0.0f;
#pragma unroll
                    for (int i = 0; i < 64; ++i)   // np-exact seq-k chain
                        acc = __builtin_fmaf(efs[lane * 65 + i], xfb[fi * 65 + i], acc);
                    float ck = Srow[fbrows[fi]] + e2l[T2 * 64 + lane];
                    float u = __builtin_fmaf(-2.0f, acc, ck);
                    u64 pk = ((u64)flipf(u) << 10) | (unsigned)(T2 * 64 + lane);
                    pmin[sl] = pmin[sl] < pk ? pmin[sl] : pk;
                }
            }
        }
#pragma unroll
        for (int sl = 0; sl < NSL; ++sl) {
            const int fi = w + 8 * sl;
            if (fi < cnt) {
                u64 pk = pmin[sl];
#pragma unroll
                for (int dl = 32; dl > 0; dl >>= 1) {
                    u64 o = __shfl_xor(pk, dl);
                    pk = o < pk ? o : pk;
                }
                if (lane == 0) kwin[fbrows[fi]] = (int)(pk & 1023u);
            }
        }
        __syncthreads();
    }

    // Epilogue: idx, quant_out = emb[kwin] (exact), loss sum.
    if (tid < RPB) out[NELEM + 2 + row0 + tid] = (float)kwin[tid];

    const int r = tid & 127, c0 = (tid >> 7) * 16;
    const int kw = kwin[r];
    const float* eqr = emb + (size_t)kw * DD;
    float lsum = 0.0f;
#pragma unroll 8
    for (int i = 0; i < 16; ++i) {
        const int c = c0 + i;
        const size_t o = (size_t)b * DD * TT + (size_t)c * TT + t0 + r;
        float qv = eqr[c];
        float xv = x[o];
        out[o] = qv;
        float a = qv - xv;
        lsum = __builtin_fmaf(a, a, lsum);
    }
#pragma unroll
    for (int off = 32; off > 0; off >>= 1) lsum += __shfl_down(lsum, off);
    if (lane == 0) atomicAdd(&bsum, lsum);
    __syncthreads();
    if (tid == 0) atomicAdd(ws + WS_LOSS, bsum);
}

__global__ void vq_finalize(const float* __restrict__ ws, float* __restrict__ out) {
    if (threadIdx.x == 0 && blockIdx.x == 0) {
        float M = ws[WS_LOSS] / (float)NELEM;
        out[NELEM + 0] = M;           // codebook_loss
        out[NELEM + 1] = 0.25f * M;   // commitment_loss = BETA * same mean
    }
}

extern "C" void kernel_launch(void* const* d_in, const int* in_sizes, int n_in,
                              void* d_out, int out_size, void* d_ws, size_t ws_size,
                              hipStream_t stream) {
    const float* x = (const float*)d_in[0];
    const float* emb = (const float*)d_in[1];
    float* out = (float*)d_out;
    float* ws = (float*)d_ws;

    vq_prep<<<KCB / 4, 256, 0, stream>>>(emb, ws);
    vq_main<<<BT / RPB, NTHR, 0, stream>>>(x, emb, out, ws);
    vq_finalize<<<1, 64, 0, stream>>>(ws, out);
}